// Round 5
// baseline (779.563 us; speedup 1.0000x reference)
//
#include <hip/hip_runtime.h>
#include <math.h>

#define NTHR 256

typedef __bf16 bf16x8 __attribute__((ext_vector_type(8)));
typedef float  f32x4  __attribute__((ext_vector_type(4)));
typedef float  f32x4v __attribute__((ext_vector_type(4)));

// Round-to-nearest-even fp32 -> bf16 bits
__device__ __forceinline__ unsigned short f2bf(float x) {
    unsigned int u = __float_as_uint(x);
    return (unsigned short)((u + 0x7fffu + ((u >> 16) & 1u)) >> 16);
}
__device__ __forceinline__ ushort4 pack4v(f32x4v v) {
    return make_ushort4(f2bf(v[0]), f2bf(v[1]), f2bf(v[2]), f2bf(v[3]));
}

// ---- Kernel R: pure streaming mean16 reduce: x3 [65536*16][128] -> x3m [65536][128]
// memcpy-shaped (m13 regime): plain float4 loads, no LDS, no barrier, one store
// per 16 loads. Wave = 2 rows x 32 lanes; per-load burst = 2 x 512 B contiguous.
__global__ __launch_bounds__(NTHR)
void reduce16_kernel(const float* __restrict__ x3, float* __restrict__ x3m)
{
    const int t   = threadIdx.x;
    const int row = blockIdx.x * 8 + (t >> 5);   // 8 out-rows per block
    const int fo  = (t & 31) * 4;
    const float* p = x3 + (size_t)row * 2048 + fo;
    f32x4v s = *(const f32x4v*)p;
    #pragma unroll
    for (int k = 1; k < 16; ++k) s += *(const f32x4v*)(p + (size_t)k * 128);
    *(f32x4v*)(x3m + (size_t)row * 128 + fo) = s * (1.0f / 16.0f);
}

// ---- SAGE layer GEMM: A-row m = [deep[m] | shal[m]] (both [M][128] fp32).
//   AGG_OUT: write mean16 over the TM relu'd output rows -> outp[M/16][128]
//   else  : write all TM rows -> outp[M][128]
// Phase 2 = MFMA 16x16x32 bf16, wave's W slice register-resident (loaded once).
template<int TM, bool AGG_OUT>
__global__ __launch_bounds__(NTHR, 4)
void layer_kernel(const float* __restrict__ deep,
                  const float* __restrict__ shal,
                  const float* __restrict__ W,
                  const float* __restrict__ bias,
                  float* __restrict__ outp)
{
    constexpr int MT = TM / 16;
    __shared__ unsigned short A[TM][264];  // bf16 bits; stride 264 -> <=2-way banks (free)
    const int t  = threadIdx.x;
    const int m0 = blockIdx.x * TM;

    // ---- Phase 1: build bf16 A-tile ----
    {
        const int r8 = t >> 5;
        const int l  = t & 31;
        const int fo = l * 4;
        for (int rr = r8; rr < TM; rr += 8) {
            const int m = m0 + rr;
            f32x4v s  = *(const f32x4v*)(deep + (size_t)m * 128 + fo);
            f32x4v sh = *(const f32x4v*)(shal + (size_t)m * 128 + fo);
            *(ushort4*)&A[rr][fo]       = pack4v(s);
            *(ushort4*)&A[rr][128 + fo] = pack4v(sh);
        }
    }

    // ---- B-fragments: wave's 32 W-cols, all 256 k, in registers (64 VGPRs) ----
    const int l    = t & 63;
    const int w    = t >> 6;
    const int lo16 = l & 15;
    const int q    = l >> 4;
    const int c0   = w * 32;

    bf16x8 Bf[16];
    #pragma unroll
    for (int kt = 0; kt < 8; ++kt) {
        #pragma unroll
        for (int nt = 0; nt < 2; ++nt) {
            const float* p = W + (size_t)(kt * 32 + q * 8) * 128 + c0 + nt * 16 + lo16;
            union { unsigned short u[8]; bf16x8 v; } tmp;
            #pragma unroll
            for (int j = 0; j < 8; ++j) tmp.u[j] = f2bf(p[(size_t)j * 128]);
            Bf[kt * 2 + nt] = tmp.v;
        }
    }
    __syncthreads();

    // ---- Phase 2: MFMA K-loop (LDS + matrix pipe only) ----
    f32x4 acc[MT][2];
    #pragma unroll
    for (int mt = 0; mt < MT; ++mt) {
        acc[mt][0] = (f32x4){0.f, 0.f, 0.f, 0.f};
        acc[mt][1] = (f32x4){0.f, 0.f, 0.f, 0.f};
    }
    #pragma unroll
    for (int kt = 0; kt < 8; ++kt) {
        #pragma unroll
        for (int mt = 0; mt < MT; ++mt) {
            bf16x8 Af = *(const bf16x8*)&A[mt * 16 + lo16][kt * 32 + q * 8];
            acc[mt][0] = __builtin_amdgcn_mfma_f32_16x16x32_bf16(Af, Bf[kt * 2 + 0], acc[mt][0], 0, 0, 0);
            acc[mt][1] = __builtin_amdgcn_mfma_f32_16x16x32_bf16(Af, Bf[kt * 2 + 1], acc[mt][1], 0, 0, 0);
        }
    }

    // ---- Epilogue: +bias, relu; store rows or reduce to block means ----
    const float bn0 = bias[c0 + lo16];
    const float bn1 = bias[c0 + 16 + lo16];
    if (AGG_OUT) {
        #pragma unroll
        for (int mt = 0; mt < MT; ++mt) {
            float v0 = 0.f, v1 = 0.f;
            #pragma unroll
            for (int r = 0; r < 4; ++r) {
                v0 += fmaxf(acc[mt][0][r] + bn0, 0.0f);
                v1 += fmaxf(acc[mt][1][r] + bn1, 0.0f);
            }
            v0 += __shfl_xor(v0, 16, 64); v0 += __shfl_xor(v0, 32, 64);
            v1 += __shfl_xor(v1, 16, 64); v1 += __shfl_xor(v1, 32, 64);
            const int g = blockIdx.x * MT + mt;
            if (q == 0) outp[(size_t)g * 128 + c0 + lo16]      = v0 * 0.0625f;
            if (q == 1) outp[(size_t)g * 128 + c0 + 16 + lo16] = v1 * 0.0625f;
        }
    } else {
        #pragma unroll
        for (int mt = 0; mt < MT; ++mt) {
            #pragma unroll
            for (int r = 0; r < 4; ++r) {
                const int row = m0 + mt * 16 + q * 4 + r;
                float* op = outp + (size_t)row * 128;
                op[c0 + lo16]      = fmaxf(acc[mt][0][r] + bn0, 0.0f);
                op[c0 + 16 + lo16] = fmaxf(acc[mt][1][r] + bn1, 0.0f);
            }
        }
    }
}

// Head: z = h0 @ lin1_W + lin1_b; BatchNorm (biased batch stats); sigmoid(zn @ lin2_W + lin2_b)
__global__ __launch_bounds__(NTHR)
void head_kernel(const float* __restrict__ h0,     // [256][128]
                 const float* __restrict__ l1W,    // [128][8]
                 const float* __restrict__ l1b,    // [8]
                 const float* __restrict__ gamma,  // [8]
                 const float* __restrict__ beta,   // [8]
                 const float* __restrict__ l2W,    // [8][2]
                 const float* __restrict__ l2b,    // [2]
                 float* __restrict__ out)          // [256][2]
{
    __shared__ float z[256][8];
    __shared__ float w1s[128 * 8];
    __shared__ float ps[32][8];
    __shared__ float pq[32][8];
    __shared__ float scale_s[8], shift_s[8];

    const int t  = threadIdx.x;
    const int j  = t & 7;
    const int rg = t >> 3;

    #pragma unroll
    for (int i = 0; i < 4; ++i) w1s[t * 4 + i] = l1W[t * 4 + i];
    __syncthreads();

    const float bj = l1b[j];
    for (int it = 0; it < 8; ++it) {
        const int b = it * 32 + rg;
        const float4* hr = (const float4*)(h0 + (size_t)b * 128);
        float s = bj;
        #pragma unroll
        for (int f4 = 0; f4 < 32; ++f4) {
            float4 h = hr[f4];
            s += h.x * w1s[(f4 * 4 + 0) * 8 + j];
            s += h.y * w1s[(f4 * 4 + 1) * 8 + j];
            s += h.z * w1s[(f4 * 4 + 2) * 8 + j];
            s += h.w * w1s[(f4 * 4 + 3) * 8 + j];
        }
        z[b][j] = s;
    }
    __syncthreads();

    {
        float s = 0.0f, qq = 0.0f;
        #pragma unroll
        for (int r = 0; r < 8; ++r) {
            float v = z[rg * 8 + r][j];
            s += v; qq += v * v;
        }
        ps[rg][j] = s; pq[rg][j] = qq;
    }
    __syncthreads();

    if (t < 8) {
        float s = 0.0f, qq = 0.0f;
        #pragma unroll
        for (int p = 0; p < 32; ++p) { s += ps[p][t]; qq += pq[p][t]; }
        const float mu  = s * (1.0f / 256.0f);
        const float var = qq * (1.0f / 256.0f) - mu * mu;
        const float sc  = gamma[t] * rsqrtf(var + 1e-5f);
        scale_s[t] = sc;
        shift_s[t] = beta[t] - mu * sc;
    }
    __syncthreads();

    {
        float o0 = l2b[0], o1 = l2b[1];
        #pragma unroll
        for (int jj = 0; jj < 8; ++jj) {
            const float zn = z[t][jj] * scale_s[jj] + shift_s[jj];
            o0 += zn * l2W[jj * 2 + 0];
            o1 += zn * l2W[jj * 2 + 1];
        }
        out[t * 2 + 0] = 1.0f / (1.0f + expf(-o0));
        out[t * 2 + 1] = 1.0f / (1.0f + expf(-o1));
    }
}

extern "C" void kernel_launch(void* const* d_in, const int* in_sizes, int n_in,
                              void* d_out, int out_size, void* d_ws, size_t ws_size,
                              hipStream_t stream)
{
    const float* x0    = (const float*)d_in[0];
    const float* x1    = (const float*)d_in[1];
    const float* x2    = (const float*)d_in[2];
    const float* x3    = (const float*)d_in[3];
    const float* W0    = (const float*)d_in[4];
    const float* b0    = (const float*)d_in[5];
    const float* W1    = (const float*)d_in[6];
    const float* b1    = (const float*)d_in[7];
    const float* W2    = (const float*)d_in[8];
    const float* b2    = (const float*)d_in[9];
    const float* l1W   = (const float*)d_in[10];
    const float* l1b   = (const float*)d_in[11];
    const float* gamma = (const float*)d_in[12];
    const float* beta  = (const float*)d_in[13];
    const float* l2W   = (const float*)d_in[14];
    const float* l2b   = (const float*)d_in[15];
    float* out = (float*)d_out;

    float* x3m = (float*)d_ws;                       // [65536][128] fp32 = 33.6 MB
    float* h2m = x3m + (size_t)65536 * 128;          // [4096][128]  = 2.1 MB
    float* h1m = h2m + (size_t)4096 * 128;           // [256][128]
    float* h0  = h1m + (size_t)256 * 128;            // [256][128]

    // 1) Pure streaming reduce: x3 -> x3m (94% of all bytes, memcpy regime)
    hipLaunchKernelGGL(reduce16_kernel, dim3(65536 / 8), dim3(NTHR), 0, stream,
                       x3, x3m);
    // 2) Layer 3 GEMM on [x3m | x2] (65536 rows) -> mean-reduced h2m [4096][128]
    hipLaunchKernelGGL((layer_kernel<64, true>), dim3(65536 / 64), dim3(NTHR), 0, stream,
                       x3m, x2, W2, b2, h2m);
    // 3) Layer 2 GEMM on [h2m | x1] (4096 rows) -> mean-reduced h1m [256][128]
    hipLaunchKernelGGL((layer_kernel<64, true>), dim3(4096 / 64), dim3(NTHR), 0, stream,
                       h2m, x1, W1, b1, h1m);
    // 4) Layer 1 GEMM on [h1m | x0] (256 rows) -> h0 [256][128]
    hipLaunchKernelGGL((layer_kernel<64, false>), dim3(256 / 64), dim3(NTHR), 0, stream,
                       h1m, x0, W0, b0, h0);
    // 5) Head
    hipLaunchKernelGGL(head_kernel, dim3(1), dim3(NTHR), 0, stream,
                       h0, l1W, l1b, gamma, beta, l2W, l2b, out);
}